// Round 3
// baseline (342.911 us; speedup 1.0000x reference)
//
#include <hip/hip_runtime.h>
#include <hip/hip_bf16.h>

#define EPS 1e-5f

typedef __attribute__((ext_vector_type(8))) short short8;
typedef __attribute__((ext_vector_type(4))) float floatx4;

__device__ inline float b2f(short s) {
    union { unsigned u; float f; } v;
    v.u = ((unsigned)(unsigned short)s) << 16;
    return v.f;
}
__device__ inline float sigmoidf_(float x) { return 1.f / (1.f + __expf(-x)); }
__device__ inline float tanhf_(float x) { return 1.f - 2.f / (__expf(2.f * x) + 1.f); }

__device__ inline void load_lds16(const void* g, void* l) {
    __builtin_amdgcn_global_load_lds(
        (const __attribute__((address_space(1))) void*)g,
        (__attribute__((address_space(3))) void*)l, 16, 0, 0);
}

// ---------------------------------------------------------------------------
// fp32 -> bf16 converts for x, h_prev, Wi, Wh (blockIdx.y selects segment).
// ---------------------------------------------------------------------------
__global__ __launch_bounds__(256)
void cvt_bf16(const float* __restrict__ s0, __hip_bfloat16* __restrict__ d0, int n0_,
              const float* __restrict__ s1, __hip_bfloat16* __restrict__ d1, int n1_,
              const float* __restrict__ s2, __hip_bfloat16* __restrict__ d2, int n2_,
              const float* __restrict__ s3, __hip_bfloat16* __restrict__ d3, int n3_) {
    const float* s; __hip_bfloat16* d; int n;
    switch (blockIdx.y) {
        case 0:  s = s0; d = d0; n = n0_; break;
        case 1:  s = s1; d = d1; n = n1_; break;
        case 2:  s = s2; d = d2; n = n2_; break;
        default: s = s3; d = d3; n = n3_; break;
    }
    const int idx = (blockIdx.x * 256 + threadIdx.x) * 8;
    if (idx < n) {
        float4 v0 = *(const float4*)(s + idx);
        float4 v1 = *(const float4*)(s + idx + 4);
        union { short8 sv; __hip_bfloat16 h[8]; } u;
        u.h[0] = __float2bfloat16(v0.x); u.h[1] = __float2bfloat16(v0.y);
        u.h[2] = __float2bfloat16(v0.z); u.h[3] = __float2bfloat16(v0.w);
        u.h[4] = __float2bfloat16(v1.x); u.h[5] = __float2bfloat16(v1.y);
        u.h[6] = __float2bfloat16(v1.z); u.h[7] = __float2bfloat16(v1.w);
        *(short8*)(d + idx) = u.sv;
    }
}

// ---------------------------------------------------------------------------
// Dual GEMM, 256x256 tile, BK=64, 512 threads (8 waves as 2Mx4N, 128x64/wave).
// 4-phase-per-K-tile schedule, race-free by construction:
//   phase-0 top: issue ALL of tile T+1's staging (8 global_load_lds/thread)
//                into the other LDS buffer.
//   each phase: {ds_read quadrant frags; s_barrier; lgkmcnt(0);
//                setprio(1) 16 MFMA setprio(0); s_barrier}
//   end of phase 3: vmcnt(0) BEFORE the boundary barrier -> next tile's data
//                fully resident; every wave's ds_reads drained (lgkmcnt(0))
//                before it can cross, so buffer overwrite is safe.
// Loads get ~3.5 phases of MFMA cover before the drain (vs 0 in the m97
// structure), so the vmcnt(0) should be nearly free.
// Why not counted vmcnt(N): every phase reads BOTH halves of A and B (waves
// span the tile), and vmcnt is per-wave while each wave stages a slice of
// every half -> partial confirmation is impossible without cohort-partitioned
// staging (the R1 race). Full drain at max cover instead.
// XOR-chunk swizzle: inverse-swizzled global source + swizzled ds_read
// (both-sides involution, carried from the verified 128^2 kernel).
// ---------------------------------------------------------------------------
#define STAGE_HALF(P, BASE, H, KZ, DSTB) do {                                   \
    const int rs0_ = (H) * 128 + r0;                                            \
    load_lds16((P) + (size_t)((BASE) + rs0_) * K + (KZ) + ((c0 ^ (rs0_ & 7)) << 3), \
               smem + (DSTB) + ((((H) << 10) + (wave << 6)) << 3));             \
    const int rs1_ = (H) * 128 + 64 + r0;                                       \
    load_lds16((P) + (size_t)((BASE) + rs1_) * K + (KZ) + ((c0 ^ (rs1_ & 7)) << 3), \
               smem + (DSTB) + ((((H) << 10) + 512 + (wave << 6)) << 3));       \
} while (0)

#define PHASE_Q(QQ, CURB, LASTP) do {                                           \
    const int hm_ = ((QQ) >= 2) ? 1 : 0;                                        \
    const int hn_ = ((QQ) == 1 || (QQ) == 2) ? 1 : 0;                           \
    const __hip_bfloat16* At_ = smem + (CURB) * 32768;                          \
    const __hip_bfloat16* Bt_ = smem + (CURB) * 32768 + 16384;                  \
    short8 aF[2][4], bF[2][2];                                                  \
    _Pragma("unroll")                                                           \
    for (int kk = 0; kk < 2; ++kk) {                                            \
        const int c_ = kk * 4 + quad;                                           \
        _Pragma("unroll")                                                       \
        for (int i = 0; i < 4; ++i) {                                           \
            const int r_ = wm + hm_ * 64 + i * 16 + rl;                         \
            aF[kk][i] = *(const short8*)(At_ + ((r_ * 8 + (c_ ^ (r_ & 7))) << 3)); \
        }                                                                       \
        _Pragma("unroll")                                                       \
        for (int j = 0; j < 2; ++j) {                                           \
            const int r_ = wn + hn_ * 32 + j * 16 + rl;                         \
            bF[kk][j] = *(const short8*)(Bt_ + ((r_ * 8 + (c_ ^ (r_ & 7))) << 3)); \
        }                                                                       \
    }                                                                           \
    __builtin_amdgcn_s_barrier();                                               \
    asm volatile("s_waitcnt lgkmcnt(0)" ::: "memory");                          \
    __builtin_amdgcn_s_setprio(1);                                              \
    _Pragma("unroll")                                                           \
    for (int kk = 0; kk < 2; ++kk)                                              \
        _Pragma("unroll")                                                       \
        for (int i = 0; i < 4; ++i)                                             \
            _Pragma("unroll")                                                   \
            for (int j = 0; j < 2; ++j)                                         \
                acc[hm_ * 4 + i][hn_ * 2 + j] = __builtin_amdgcn_mfma_f32_16x16x32_bf16( \
                    aF[kk][i], bF[kk][j], acc[hm_ * 4 + i][hn_ * 2 + j], 0, 0, 0); \
    __builtin_amdgcn_s_setprio(0);                                              \
    if (LASTP) asm volatile("s_waitcnt vmcnt(0)" ::: "memory");                 \
    __builtin_amdgcn_s_barrier();                                               \
} while (0)

__global__ __launch_bounds__(512, 2)
void gemm_dual(const __hip_bfloat16* __restrict__ A0, const __hip_bfloat16* __restrict__ W0,
               const float* __restrict__ bias0, __hip_bfloat16* __restrict__ out0, int K0,
               const __hip_bfloat16* __restrict__ A1, const __hip_bfloat16* __restrict__ W1,
               const float* __restrict__ bias1, __hip_bfloat16* __restrict__ out1, int K1) {
    __shared__ alignas(16) __hip_bfloat16 smem[65536];   // 128 KiB

    const __hip_bfloat16* A;  const __hip_bfloat16* W;
    const float* bias;        __hip_bfloat16* out;  int K;
    if (blockIdx.y == 0) { A = A0; W = W0; bias = bias0; out = out0; K = K0; }
    else                 { A = A1; W = W1; bias = bias1; out = out1; K = K1; }

    const int t    = threadIdx.x;
    const int lane = t & 63;
    const int wave = t >> 6;
    const int quad = lane >> 4;
    const int rl   = lane & 15;
    const int wm   = (wave >> 2) * 128;   // 2 waves along M
    const int wn   = (wave & 3) * 64;     // 4 waves along N

    // XCD-aware swizzle: 512 blocks/plane, 512 % 8 == 0 -> bijective simple form
    const int id  = blockIdx.x;
    const int swz = (id & 7) * 64 + (id >> 3);
    const int m0  = (swz >> 4) * 256;     // 32 M-tiles
    const int n0  = (swz & 15) * 256;     // 16 N-tiles

    const int r0 = t >> 3;                // 0..63: row within stage slice
    const int c0 = t & 7;                 // 16B chunk col

    floatx4 acc[8][4];
    #pragma unroll
    for (int i = 0; i < 8; ++i)
        #pragma unroll
        for (int j = 0; j < 4; ++j)
            acc[i][j] = (floatx4){0.f, 0.f, 0.f, 0.f};

    // prologue: stage tile 0 -> buf0, full drain, barrier
    STAGE_HALF(A, m0, 0, 0, 0);
    STAGE_HALF(W, n0, 0, 0, 16384);
    STAGE_HALF(W, n0, 1, 0, 16384);
    STAGE_HALF(A, m0, 1, 0, 0);
    asm volatile("s_waitcnt vmcnt(0)" ::: "memory");
    __builtin_amdgcn_s_barrier();

    const int NT = K >> 6;
    for (int T = 0; T < NT; ++T) {
        const int cur = T & 1;
        if (T + 1 < NT) {   // issue ALL of tile T+1's staging at phase-0 top
            const int kn = (T + 1) << 6;
            const int ab = (cur ^ 1) * 32768;
            const int bb = ab + 16384;
            STAGE_HALF(A, m0, 0, kn, ab);
            STAGE_HALF(W, n0, 0, kn, bb);
            STAGE_HALF(W, n0, 1, kn, bb);
            STAGE_HALF(A, m0, 1, kn, ab);
        }
        PHASE_Q(0, cur, 0);
        PHASE_Q(1, cur, 0);
        PHASE_Q(2, cur, 0);
        PHASE_Q(3, cur, 1);   // vmcnt(0) before boundary barrier
    }

    // epilogue: per m-half LDS repack (stride 264) -> coalesced 16B stores
    __syncthreads();
    const int wh = wave >> 2;
    #pragma unroll
    for (int h = 0; h < 2; ++h) {
        if (wh == h) {
            #pragma unroll
            for (int jc = 0; jc < 4; ++jc) {
                const int col = wn + jc * 16 + rl;
                const float bv = bias[n0 + col];
                #pragma unroll
                for (int im = 0; im < 8; ++im) {
                    const int rloc = im * 16 + quad * 4;
                    #pragma unroll
                    for (int rr = 0; rr < 4; ++rr)
                        smem[(rloc + rr) * 264 + col] = __float2bfloat16(acc[im][jc][rr] + bv);
                }
            }
        }
        __syncthreads();
        #pragma unroll
        for (int p = 0; p < 8; ++p) {
            const int ch  = p * 512 + t;
            const int row = ch >> 5;
            const int c8  = (ch & 31) << 3;
            short8 v = *(const short8*)(smem + row * 264 + c8);
            *(short8*)(out + (size_t)(m0 + h * 128 + row) * 4096 + n0 + c8) = v;
        }
        __syncthreads();
    }
}

// ---------------------------------------------------------------------------
// Single-pass LN+gates, 2 rows per block (128 threads/row), all 16B loads.
// (unchanged)
// ---------------------------------------------------------------------------
__global__ __launch_bounds__(256)
void ln_gates(const __hip_bfloat16* __restrict__ Pi, const __hip_bfloat16* __restrict__ Ph,
              const float* __restrict__ c_prev,
              const float* __restrict__ g_in, const float* __restrict__ b_in,
              const float* __restrict__ g_hid, const float* __restrict__ b_hid,
              const float* __restrict__ g_cell, const float* __restrict__ b_cell,
              float* __restrict__ h_out, float* __restrict__ c_out) {
    const int t    = threadIdx.x;
    const int half = t >> 7;
    const int tt   = t & 127;
    const int wave = t >> 6;
    const int row  = blockIdx.x * 2 + half;
    __shared__ float sred[4][6];

    const __hip_bfloat16* pi = Pi + (size_t)row * 4096;
    const __hip_bfloat16* ph = Ph + (size_t)row * 4096;
    const int j0 = tt * 8;

    float fpi[4][8], fph[4][8];
    float si = 0.f, sqi = 0.f, sh = 0.f, sqh = 0.f;
    #pragma unroll
    for (int g = 0; g < 4; ++g) {
        short8 vi = *(const short8*)(pi + g * 1024 + j0);
        short8 vh = *(const short8*)(ph + g * 1024 + j0);
        #pragma unroll
        for (int e = 0; e < 8; ++e) {
            const float a = b2f(vi[e]); fpi[g][e] = a; si += a; sqi += a * a;
            const float b = b2f(vh[e]); fph[g][e] = b; sh += b; sqh += b * b;
        }
    }
    floatx4 cp0 = *(const floatx4*)(c_prev + (size_t)row * 1024 + j0);
    floatx4 cp1 = *(const floatx4*)(c_prev + (size_t)row * 1024 + j0 + 4);

    #pragma unroll
    for (int mask = 1; mask <= 32; mask <<= 1) {
        si += __shfl_xor(si, mask); sqi += __shfl_xor(sqi, mask);
        sh += __shfl_xor(sh, mask); sqh += __shfl_xor(sqh, mask);
    }
    if ((t & 63) == 0) {
        sred[wave][0] = si; sred[wave][1] = sqi;
        sred[wave][2] = sh; sred[wave][3] = sqh;
    }
    __syncthreads();
    const int wb = half * 2;
    si  = sred[wb][0] + sred[wb + 1][0];
    sqi = sred[wb][1] + sred[wb + 1][1];
    sh  = sred[wb][2] + sred[wb + 1][2];
    sqh = sred[wb][3] + sred[wb + 1][3];

    const float mu_i = si * (1.f / 4096.f);
    const float rs_i = rsqrtf(sqi * (1.f / 4096.f) - mu_i * mu_i + EPS);
    const float mu_h = sh * (1.f / 4096.f);
    const float rs_h = rsqrtf(sqh * (1.f / 4096.f) - mu_h * mu_h + EPS);

    float comb[4][8];
    #pragma unroll
    for (int g = 0; g < 4; ++g) {
        const int col = g * 1024 + j0;
        floatx4 gi0  = *(const floatx4*)(g_in  + col);
        floatx4 gi1  = *(const floatx4*)(g_in  + col + 4);
        floatx4 bi0  = *(const floatx4*)(b_in  + col);
        floatx4 bi1  = *(const floatx4*)(b_in  + col + 4);
        floatx4 gh0  = *(const floatx4*)(g_hid + col);
        floatx4 gh1  = *(const floatx4*)(g_hid + col + 4);
        floatx4 bh0  = *(const floatx4*)(b_hid + col);
        floatx4 bh1  = *(const floatx4*)(b_hid + col + 4);
        #pragma unroll
        for (int e = 0; e < 4; ++e) {
            comb[g][e]     = (fpi[g][e]     - mu_i) * rs_i * gi0[e] + bi0[e]
                           + (fph[g][e]     - mu_h) * rs_h * gh0[e] + bh0[e];
            comb[g][e + 4] = (fpi[g][e + 4] - mu_i) * rs_i * gi1[e] + bi1[e]
                           + (fph[g][e + 4] - mu_h) * rs_h * gh1[e] + bh1[e];
        }
    }

    float cn[8], ov[8];
    float sc = 0.f, scq = 0.f;
    #pragma unroll
    for (int e = 0; e < 8; ++e) {
        const float iv = sigmoidf_(comb[0][e]);
        const float fv = sigmoidf_(comb[1][e]);
        const float gv = tanhf_(comb[2][e]);
        ov[e] = sigmoidf_(comb[3][e]);
        const float cpv = (e < 4) ? cp0[e] : cp1[e - 4];
        const float c = fv * cpv + iv * gv;
        cn[e] = c; sc += c; scq += c * c;
    }
    #pragma unroll
    for (int mask = 1; mask <= 32; mask <<= 1) {
        sc += __shfl_xor(sc, mask); scq += __shfl_xor(scq, mask);
    }
    if ((t & 63) == 0) { sred[wave][4] = sc; sred[wave][5] = scq; }
    __syncthreads();
    sc  = sred[wb][4] + sred[wb + 1][4];
    scq = sred[wb][5] + sred[wb + 1][5];
    const float mu_c = sc * (1.f / 1024.f);
    const float rs_c = rsqrtf(scq * (1.f / 1024.f) - mu_c * mu_c + EPS);

    floatx4 gc0 = *(const floatx4*)(g_cell + j0);
    floatx4 gc1 = *(const floatx4*)(g_cell + j0 + 4);
    floatx4 bc0 = *(const floatx4*)(b_cell + j0);
    floatx4 bc1 = *(const floatx4*)(b_cell + j0 + 4);
    floatx4 hv0, hv1, cv0, cv1;
    #pragma unroll
    for (int e = 0; e < 4; ++e) {
        const float nc0 = (cn[e]     - mu_c) * rs_c * gc0[e] + bc0[e];
        const float nc1 = (cn[e + 4] - mu_c) * rs_c * gc1[e] + bc1[e];
        hv0[e] = ov[e] * tanhf_(nc0);
        hv1[e] = ov[e + 4] * tanhf_(nc1);
        cv0[e] = cn[e];
        cv1[e] = cn[e + 4];
    }
    float* hp = h_out + (size_t)row * 1024 + j0;
    float* cpout = c_out + (size_t)row * 1024 + j0;
    *(floatx4*)(hp) = hv0;     *(floatx4*)(hp + 4) = hv1;
    *(floatx4*)(cpout) = cv0;  *(floatx4*)(cpout + 4) = cv1;
}

// ---------------------------------------------------------------------------
extern "C" void kernel_launch(void* const* d_in, const int* in_sizes, int n_in,
                              void* d_out, int out_size, void* d_ws, size_t ws_size,
                              hipStream_t stream) {
    const float* x      = (const float*)d_in[0];
    const float* h_prev = (const float*)d_in[1];
    const float* c_prev = (const float*)d_in[2];
    const float* Wi     = (const float*)d_in[3];
    const float* bi     = (const float*)d_in[4];
    const float* Wh     = (const float*)d_in[5];
    const float* bh     = (const float*)d_in[6];
    const float* g_in   = (const float*)d_in[7];
    const float* b_in   = (const float*)d_in[8];
    const float* g_hid  = (const float*)d_in[9];
    const float* b_hid  = (const float*)d_in[10];
    const float* g_cell = (const float*)d_in[11];
    const float* b_cell = (const float*)d_in[12];

    __hip_bfloat16* Pi = (__hip_bfloat16*)d_ws;               // 64 MiB
    __hip_bfloat16* Ph = Pi + (size_t)8192 * 4096;            // 64 MiB

    const int NX = 8192 * 512, NH = 8192 * 1024, NWI = 4096 * 512, NWH = 4096 * 1024;
    __hip_bfloat16* xb  = (__hip_bfloat16*)d_out;
    __hip_bfloat16* hb  = xb + NX;
    __hip_bfloat16* Wib = hb + NH;
    __hip_bfloat16* Whb = Wib + NWI;

    float* h_out = (float*)d_out;
    float* c_out = h_out + (size_t)8192 * 1024;

    hipLaunchKernelGGL(cvt_bf16, dim3(4096, 4), dim3(256), 0, stream,
                       x, xb, NX, h_prev, hb, NH, Wi, Wib, NWI, Wh, Whb, NWH);

    // 256^2 tiles: 32 M-tiles x 16 N-tiles = 512 blocks per GEMM, y selects GEMM
    hipLaunchKernelGGL(gemm_dual, dim3(512, 2), dim3(512), 0, stream,
                       xb, Wib, bi, Pi, 512,
                       hb, Whb, bh, Ph, 1024);

    hipLaunchKernelGGL(ln_gates, dim3(4096), dim3(256), 0, stream, Pi, Ph, c_prev,
                       g_in, b_in, g_hid, b_hid, g_cell, b_cell, h_out, c_out);
}

// Round 4
// 310.008 us; speedup vs baseline: 1.1061x; 1.1061x over previous
//
#include <hip/hip_runtime.h>
#include <hip/hip_bf16.h>

#define EPS 1e-5f

typedef __attribute__((ext_vector_type(8))) short short8;
typedef __attribute__((ext_vector_type(4))) float floatx4;

__device__ inline float b2f(short s) {
    union { unsigned u; float f; } v;
    v.u = ((unsigned)(unsigned short)s) << 16;
    return v.f;
}
__device__ inline float sigmoidf_(float x) { return 1.f / (1.f + __expf(-x)); }
__device__ inline float tanhf_(float x) { return 1.f - 2.f / (__expf(2.f * x) + 1.f); }

__device__ inline void load_lds16(const void* g, void* l) {
    __builtin_amdgcn_global_load_lds(
        (const __attribute__((address_space(1))) void*)g,
        (__attribute__((address_space(3))) void*)l, 16, 0, 0);
}

// ---------------------------------------------------------------------------
// fp32 -> bf16 converts for x, h_prev, Wi, Wh.  Exact 1-D grid (9216 blocks):
//   [0,2048) x | [2048,6144) h | [6144,7168) Wi | [7168,9216) Wh
// Every block is full (all segment sizes are multiples of 2048 elems).
// ---------------------------------------------------------------------------
__global__ __launch_bounds__(256)
void cvt_bf16(const float* __restrict__ s0, __hip_bfloat16* __restrict__ d0,
              const float* __restrict__ s1, __hip_bfloat16* __restrict__ d1,
              const float* __restrict__ s2, __hip_bfloat16* __restrict__ d2,
              const float* __restrict__ s3, __hip_bfloat16* __restrict__ d3) {
    const int b = blockIdx.x;
    const float* s; __hip_bfloat16* d; int off;
    if (b < 2048)      { s = s0; d = d0; off = b; }
    else if (b < 6144) { s = s1; d = d1; off = b - 2048; }
    else if (b < 7168) { s = s2; d = d2; off = b - 6144; }
    else               { s = s3; d = d3; off = b - 7168; }
    const int idx = (off * 256 + threadIdx.x) * 8;
    float4 v0 = *(const float4*)(s + idx);
    float4 v1 = *(const float4*)(s + idx + 4);
    union { short8 sv; __hip_bfloat16 h[8]; } u;
    u.h[0] = __float2bfloat16(v0.x); u.h[1] = __float2bfloat16(v0.y);
    u.h[2] = __float2bfloat16(v0.z); u.h[3] = __float2bfloat16(v0.w);
    u.h[4] = __float2bfloat16(v1.x); u.h[5] = __float2bfloat16(v1.y);
    u.h[6] = __float2bfloat16(v1.z); u.h[7] = __float2bfloat16(v1.w);
    *(short8*)(d + idx) = u.sv;
}

// ---------------------------------------------------------------------------
// Dual GEMM in one dispatch: blockIdx.z selects {A,W,bias,out,K}.
// 128x128 tile, BK=64, 4 waves (2x2), 4x4 mfma_f32_16x16x32_bf16 per wave.
// Staging: global_load_lds width=16, XOR-swizzled chunks.
// Epilogue: acc+bias -> padded LDS (stride 136) -> coalesced 16B stores.
// ~974 TF for the pair (verified R0, 106 us) — m97-structure ceiling.
// R3 lesson: 256^2 4-phase with drain-vmcnt(0) = 644 TF (matches the guide's
// drain0 ≈ 2-phase regime gate); counted-vmcnt choreography is the only way
// past this, deferred until the aux slack question is settled.
// ---------------------------------------------------------------------------
__global__ __launch_bounds__(256, 3)
void gemm_dual(const __hip_bfloat16* __restrict__ A0, const __hip_bfloat16* __restrict__ W0,
               const float* __restrict__ bias0, __hip_bfloat16* __restrict__ out0, int K0,
               const __hip_bfloat16* __restrict__ A1, const __hip_bfloat16* __restrict__ W1,
               const float* __restrict__ bias1, __hip_bfloat16* __restrict__ out1, int K1) {
    __shared__ alignas(16) __hip_bfloat16 smem[17408];
    __hip_bfloat16* sA = smem;
    __hip_bfloat16* sB = smem + 8192;

    const __hip_bfloat16* A;  const __hip_bfloat16* W;
    const float* bias;        __hip_bfloat16* out;  int K;
    if (blockIdx.z == 0) { A = A0; W = W0; bias = bias0; out = out0; K = K0; }
    else                 { A = A1; W = W1; bias = bias1; out = out1; K = K1; }

    const int t    = threadIdx.x;
    const int lane = t & 63;
    const int wave = t >> 6;
    const int quad = lane >> 4;
    const int rl   = lane & 15;
    const int wm   = (wave >> 1) * 64;
    const int wn   = (wave & 1) * 64;
    const int m0   = blockIdx.y * 128;
    const int n0   = blockIdx.x * 128;

    floatx4 acc[4][4];
    #pragma unroll
    for (int i = 0; i < 4; ++i)
        #pragma unroll
        for (int j = 0; j < 4; ++j)
            acc[i][j] = (floatx4){0.f, 0.f, 0.f, 0.f};

    int srow[4], scol[4];
    #pragma unroll
    for (int i = 0; i < 4; ++i) {
        const int cl  = (wave * 4 + i) * 64 + lane;
        const int row = cl >> 3;
        srow[i] = row;
        scol[i] = ((cl & 7) ^ (row & 7)) * 8;
    }

    for (int k0 = 0; k0 < K; k0 += 64) {
        __syncthreads();
        #pragma unroll
        for (int i = 0; i < 4; ++i) {
            load_lds16(A + (size_t)(m0 + srow[i]) * K + k0 + scol[i], sA + (wave * 4 + i) * 512);
            load_lds16(W + (size_t)(n0 + srow[i]) * K + k0 + scol[i], sB + (wave * 4 + i) * 512);
        }
        __syncthreads();
        #pragma unroll
        for (int kk = 0; kk < 2; ++kk) {
            short8 aF[4], bF[4];
            #pragma unroll
            for (int i = 0; i < 4; ++i) {
                const int r = wm + i * 16 + rl;
                const int c = kk * 4 + quad;
                aF[i] = *(const short8*)(sA + (r * 8 + (c ^ (r & 7))) * 8);
            }
            #pragma unroll
            for (int j = 0; j < 4; ++j) {
                const int r = wn + j * 16 + rl;
                const int c = kk * 4 + quad;
                bF[j] = *(const short8*)(sB + (r * 8 + (c ^ (r & 7))) * 8);
            }
            #pragma unroll
            for (int i = 0; i < 4; ++i)
                #pragma unroll
                for (int j = 0; j < 4; ++j)
                    acc[i][j] = __builtin_amdgcn_mfma_f32_16x16x32_bf16(aF[i], bF[j], acc[i][j], 0, 0, 0);
        }
    }

    __syncthreads();
    #pragma unroll
    for (int j = 0; j < 4; ++j) {
        const int col = wn + j * 16 + rl;
        const float bv = bias[n0 + col];
        #pragma unroll
        for (int i = 0; i < 4; ++i) {
            const int rbase = wm + i * 16 + quad * 4;
            #pragma unroll
            for (int r = 0; r < 4; ++r)
                smem[(rbase + r) * 136 + col] = __float2bfloat16(acc[i][j][r] + bv);
        }
    }
    __syncthreads();
    #pragma unroll
    for (int p = 0; p < 8; ++p) {
        const int ch  = p * 256 + t;
        const int row = ch >> 4;
        const int c8  = (ch & 15) * 8;
        short8 v = *(const short8*)(smem + row * 136 + c8);
        *(short8*)(out + (size_t)(m0 + row) * 4096 + n0 + c8) = v;
    }
}

// ---------------------------------------------------------------------------
// Single-pass LN+gates, now 4 rows per block (512 threads, 128/row).
// Per-thread code identical to the verified 256-thread version; only the
// row/wave bookkeeping is generalized (rid = t>>7, sred[8][6]).
// ---------------------------------------------------------------------------
__global__ __launch_bounds__(512)
void ln_gates(const __hip_bfloat16* __restrict__ Pi, const __hip_bfloat16* __restrict__ Ph,
              const float* __restrict__ c_prev,
              const float* __restrict__ g_in, const float* __restrict__ b_in,
              const float* __restrict__ g_hid, const float* __restrict__ b_hid,
              const float* __restrict__ g_cell, const float* __restrict__ b_cell,
              float* __restrict__ h_out, float* __restrict__ c_out) {
    const int t    = threadIdx.x;
    const int rid  = t >> 7;                 // row within block (0..3)
    const int tt   = t & 127;
    const int wave = t >> 6;                 // 0..7 (waves 2r,2r+1 -> row r)
    const int row  = blockIdx.x * 4 + rid;
    __shared__ float sred[8][6];

    const __hip_bfloat16* pi = Pi + (size_t)row * 4096;
    const __hip_bfloat16* ph = Ph + (size_t)row * 4096;
    const int j0 = tt * 8;

    float fpi[4][8], fph[4][8];
    float si = 0.f, sqi = 0.f, sh = 0.f, sqh = 0.f;
    #pragma unroll
    for (int g = 0; g < 4; ++g) {
        short8 vi = *(const short8*)(pi + g * 1024 + j0);
        short8 vh = *(const short8*)(ph + g * 1024 + j0);
        #pragma unroll
        for (int e = 0; e < 8; ++e) {
            const float a = b2f(vi[e]); fpi[g][e] = a; si += a; sqi += a * a;
            const float b = b2f(vh[e]); fph[g][e] = b; sh += b; sqh += b * b;
        }
    }
    floatx4 cp0 = *(const floatx4*)(c_prev + (size_t)row * 1024 + j0);
    floatx4 cp1 = *(const floatx4*)(c_prev + (size_t)row * 1024 + j0 + 4);

    #pragma unroll
    for (int mask = 1; mask <= 32; mask <<= 1) {
        si += __shfl_xor(si, mask); sqi += __shfl_xor(sqi, mask);
        sh += __shfl_xor(sh, mask); sqh += __shfl_xor(sqh, mask);
    }
    if ((t & 63) == 0) {
        sred[wave][0] = si; sred[wave][1] = sqi;
        sred[wave][2] = sh; sred[wave][3] = sqh;
    }
    __syncthreads();
    const int wb = rid * 2;
    si  = sred[wb][0] + sred[wb + 1][0];
    sqi = sred[wb][1] + sred[wb + 1][1];
    sh  = sred[wb][2] + sred[wb + 1][2];
    sqh = sred[wb][3] + sred[wb + 1][3];

    const float mu_i = si * (1.f / 4096.f);
    const float rs_i = rsqrtf(sqi * (1.f / 4096.f) - mu_i * mu_i + EPS);
    const float mu_h = sh * (1.f / 4096.f);
    const float rs_h = rsqrtf(sqh * (1.f / 4096.f) - mu_h * mu_h + EPS);

    float comb[4][8];
    #pragma unroll
    for (int g = 0; g < 4; ++g) {
        const int col = g * 1024 + j0;
        floatx4 gi0  = *(const floatx4*)(g_in  + col);
        floatx4 gi1  = *(const floatx4*)(g_in  + col + 4);
        floatx4 bi0  = *(const floatx4*)(b_in  + col);
        floatx4 bi1  = *(const floatx4*)(b_in  + col + 4);
        floatx4 gh0  = *(const floatx4*)(g_hid + col);
        floatx4 gh1  = *(const floatx4*)(g_hid + col + 4);
        floatx4 bh0  = *(const floatx4*)(b_hid + col);
        floatx4 bh1  = *(const floatx4*)(b_hid + col + 4);
        #pragma unroll
        for (int e = 0; e < 4; ++e) {
            comb[g][e]     = (fpi[g][e]     - mu_i) * rs_i * gi0[e] + bi0[e]
                           + (fph[g][e]     - mu_h) * rs_h * gh0[e] + bh0[e];
            comb[g][e + 4] = (fpi[g][e + 4] - mu_i) * rs_i * gi1[e] + bi1[e]
                           + (fph[g][e + 4] - mu_h) * rs_h * gh1[e] + bh1[e];
        }
    }

    float cn[8], ov[8];
    float sc = 0.f, scq = 0.f;
    #pragma unroll
    for (int e = 0; e < 8; ++e) {
        const float iv = sigmoidf_(comb[0][e]);
        const float fv = sigmoidf_(comb[1][e]);
        const float gv = tanhf_(comb[2][e]);
        ov[e] = sigmoidf_(comb[3][e]);
        const float cpv = (e < 4) ? cp0[e] : cp1[e - 4];
        const float c = fv * cpv + iv * gv;
        cn[e] = c; sc += c; scq += c * c;
    }
    #pragma unroll
    for (int mask = 1; mask <= 32; mask <<= 1) {
        sc += __shfl_xor(sc, mask); scq += __shfl_xor(scq, mask);
    }
    if ((t & 63) == 0) { sred[wave][4] = sc; sred[wave][5] = scq; }
    __syncthreads();
    sc  = sred[wb][4] + sred[wb + 1][4];
    scq = sred[wb][5] + sred[wb + 1][5];
    const float mu_c = sc * (1.f / 1024.f);
    const float rs_c = rsqrtf(scq * (1.f / 1024.f) - mu_c * mu_c + EPS);

    floatx4 gc0 = *(const floatx4*)(g_cell + j0);
    floatx4 gc1 = *(const floatx4*)(g_cell + j0 + 4);
    floatx4 bc0 = *(const floatx4*)(b_cell + j0);
    floatx4 bc1 = *(const floatx4*)(b_cell + j0 + 4);
    floatx4 hv0, hv1, cv0, cv1;
    #pragma unroll
    for (int e = 0; e < 4; ++e) {
        const float nc0 = (cn[e]     - mu_c) * rs_c * gc0[e] + bc0[e];
        const float nc1 = (cn[e + 4] - mu_c) * rs_c * gc1[e] + bc1[e];
        hv0[e] = ov[e] * tanhf_(nc0);
        hv1[e] = ov[e + 4] * tanhf_(nc1);
        cv0[e] = cn[e];
        cv1[e] = cn[e + 4];
    }
    float* hp = h_out + (size_t)row * 1024 + j0;
    float* cpout = c_out + (size_t)row * 1024 + j0;
    *(floatx4*)(hp) = hv0;     *(floatx4*)(hp + 4) = hv1;
    *(floatx4*)(cpout) = cv0;  *(floatx4*)(cpout + 4) = cv1;
}

// ---------------------------------------------------------------------------
extern "C" void kernel_launch(void* const* d_in, const int* in_sizes, int n_in,
                              void* d_out, int out_size, void* d_ws, size_t ws_size,
                              hipStream_t stream) {
    const float* x      = (const float*)d_in[0];
    const float* h_prev = (const float*)d_in[1];
    const float* c_prev = (const float*)d_in[2];
    const float* Wi     = (const float*)d_in[3];
    const float* bi     = (const float*)d_in[4];
    const float* Wh     = (const float*)d_in[5];
    const float* bh     = (const float*)d_in[6];
    const float* g_in   = (const float*)d_in[7];
    const float* b_in   = (const float*)d_in[8];
    const float* g_hid  = (const float*)d_in[9];
    const float* b_hid  = (const float*)d_in[10];
    const float* g_cell = (const float*)d_in[11];
    const float* b_cell = (const float*)d_in[12];

    __hip_bfloat16* Pi = (__hip_bfloat16*)d_ws;               // 64 MiB
    __hip_bfloat16* Ph = Pi + (size_t)8192 * 4096;            // 64 MiB

    // d_out doubles as scratch for bf16-converted inputs; ln_gates fully
    // overwrites all 64 MiB of d_out at the end of every call.
    const int NX = 8192 * 512, NH = 8192 * 1024;
    __hip_bfloat16* xb  = (__hip_bfloat16*)d_out;
    __hip_bfloat16* hb  = xb + NX;
    __hip_bfloat16* Wib = hb + NH;
    __hip_bfloat16* Whb = Wib + 4096 * 512;

    float* h_out = (float*)d_out;
    float* c_out = h_out + (size_t)8192 * 1024;

    hipLaunchKernelGGL(cvt_bf16, dim3(9216), dim3(256), 0, stream,
                       x, xb, h_prev, hb, Wi, Wib, Wh, Whb);

    hipLaunchKernelGGL(gemm_dual, dim3(32, 64, 2), dim3(256), 0, stream,
                       xb, Wib, bi, Pi, 512,
                       hb, Whb, bh, Ph, 1024);

    hipLaunchKernelGGL(ln_gates, dim3(2048), dim3(512), 0, stream, Pi, Ph, c_prev,
                       g_in, b_in, g_hid, b_hid, g_cell, b_cell, h_out, c_out);
}